// Round 6
// baseline (439.048 us; speedup 1.0000x reference)
//
#include <hip/hip_runtime.h>
#include <stdint.h>

typedef __attribute__((ext_vector_type(8))) short short8;
typedef __attribute__((ext_vector_type(16))) float floatx16;

#define B_DIM 8192
#define K_DIM 2048
#define N_DIM 2048

// round-to-nearest-even fp32 -> bf16
__device__ __forceinline__ unsigned short f2bf(float f) {
    union { float f; unsigned u; } v; v.f = f;
    unsigned r = v.u + 0x7fffu + ((v.u >> 16) & 1u);
    return (unsigned short)(r >> 16);
}

__device__ __forceinline__ void gld_lds16(const void* g, void* l) {
    __builtin_amdgcn_global_load_lds(
        (const __attribute__((address_space(1))) void*)g,
        (__attribute__((address_space(3))) void*)l, 16, 0, 0);
}

// ---------------- prepass 1: X -> Xb (bf16), Lb = bf16(log(|x|+eps)) ----------------
__global__ __launch_bounds__(256) void prep_x(const float4* __restrict__ X4,
                                              ushort* __restrict__ Xb,
                                              ushort* __restrict__ Lb) {
    int i = blockIdx.x * 256 + threadIdx.x;
    float4 v = X4[i];
    ushort4 xb, lb;
    xb.x = f2bf(v.x); xb.y = f2bf(v.y); xb.z = f2bf(v.z); xb.w = f2bf(v.w);
    lb.x = f2bf(__logf(fabsf(v.x) + 1e-7f));
    lb.y = f2bf(__logf(fabsf(v.y) + 1e-7f));
    lb.z = f2bf(__logf(fabsf(v.z) + 1e-7f));
    lb.w = f2bf(__logf(fabsf(v.w) + 1e-7f));
    *(ushort4*)(Xb + (size_t)i * 4) = xb;
    *(ushort4*)(Lb + (size_t)i * 4) = lb;
}

// ---------------- prepass 2: Wt[n][k] = bf16(tanh(Wh)*sigmoid(Mh)), Gt[n][k] = bf16(gate) ----
__global__ __launch_bounds__(256) void prep_wg(const float* __restrict__ Wh,
                                               const float* __restrict__ Mh,
                                               const float* __restrict__ Gf,
                                               ushort* __restrict__ Wt,
                                               ushort* __restrict__ Gt) {
    __shared__ float tw[32][33];
    __shared__ float tg[32][33];
    const int k0 = blockIdx.y * 32, n0 = blockIdx.x * 32;
    const int tx = threadIdx.x, ty = threadIdx.y;  // 32 x 8
#pragma unroll
    for (int i = 0; i < 4; i++) {
        int k = k0 + ty + i * 8;
        int n = n0 + tx;
        size_t idx = (size_t)k * N_DIM + n;
        float wh = Wh[idx], mh = Mh[idx];
        float e2 = __expf(2.f * wh);
        float th = 1.f - 2.f / (e2 + 1.f);          // tanh(wh)
        tw[ty + i * 8][tx] = th * (1.f / (1.f + __expf(-mh)));
        tg[ty + i * 8][tx] = Gf[idx];
    }
    __syncthreads();
#pragma unroll
    for (int i = 0; i < 4; i++) {
        int n = n0 + ty + i * 8;
        int k = k0 + tx;
        Wt[(size_t)n * K_DIM + k] = f2bf(tw[tx][ty + i * 8]);
        Gt[(size_t)n * K_DIM + k] = f2bf(tg[tx][ty + i * 8]);
    }
}

// ---------------- fused GEMM: a = Xb@Wt^T, lm = Lb@Wt^T, gl = Xb@Gt^T ----------------
// out = sigmoid(gl)*a + (1-sigmoid(gl))*exp(lm)
//
// Round-6: same 4-phase counted-vmcnt schedule as r5 (267us, MfmaUtil 33%),
// two levers against MFMA ISSUE serialization (2 waves/SIMD x 12 x 19.4cy =
// 466cy/phase was the dominant serial element):
//  (1) mfma_f32_32x32x16_bf16: half the MFMA instructions (24 vs 48 per
//      wave-K-step) for the same FLOPs; measured ceiling 2495 vs 2075 TF
//      (floor 99 -> 83us). A/B frag: row = lane&31, k-chunk = (lane>>5)*8
//      (direct analog of the verified 16x16 pattern). kk=1 adds byte 32
//      which is INSIDE the XOR-swizzle mask (bits 4-6) -> separate base reg
//      per kk, not an additive offset. C/D: col=lane&31,
//      row=(r&3)+8*(r>>2)+4*(lane>>5) [m74/m101] -> epilogue stores are
//      128B-contiguous per half-wave (fixes write amplification: WRITE_SIZE
//      was 96MB vs 64MB ideal).
//  (2) stage spread m201-style: X/L (4 gld_lds) in PH2, W/G (2) in PH3
//      instead of all 6 in PH3. WAR: X/L last read PH1 -> staged PH2 behind
//      PH1's collective lgkm0+barrier; W/G last read PH2 -> staged PH3.
// Carried: BM=256 BN=128 BK=32, 8 waves (4Mx2N), wave tile 64x64; 3 x 48KB
// rotating buffers, VM12 steady / VM6 / VM0 tails; raw s_barrier only; T2
// XOR bank-swizzle (linear gld_lds dest, swizzle-inverse global source, XOR
// on read addr) — conflict-free for the 32-row read pattern too (verified:
// quads ((r&1)<<2|c)^(r&7) cover all 8, 8 lanes each).
#define BUFE 24576            // elems per buffer (48 KB): X 8192 | L 8192 | W 4096 | G 4096

__global__ __launch_bounds__(512, 2) void gemm_fused(const ushort* __restrict__ Xb,
                                                     const ushort* __restrict__ Lb,
                                                     const ushort* __restrict__ Wt,
                                                     const ushort* __restrict__ Gt,
                                                     float* __restrict__ out) {
    extern __shared__ ushort smem[];

    const int t = threadIdx.x;          // 0..511
    const int lane = t & 63;
    const int w = t >> 6;               // 0..7
    const int wm = w >> 1;              // 0..3 (M quadrant)
    const int wn = w & 1;               // 0..1 (N half)
    const int rowA = blockIdx.y * 256;  // M tile base
    const int rowB = blockIdx.x * 128;  // N tile base

    floatx16 acca[2][2], accm[2][2], accg[2][2];
#pragma unroll
    for (int i = 0; i < 2; i++)
#pragma unroll
        for (int j = 0; j < 2; j++) {
            floatx16 zz = {0.f,0.f,0.f,0.f,0.f,0.f,0.f,0.f,
                           0.f,0.f,0.f,0.f,0.f,0.f,0.f,0.f};
            acca[i][j] = zz; accm[i][j] = zz; accg[i][j] = zz;
        }

    // ---- staging: swizzle-inverse source coordinates -------------------------
    // dest byte d holds global (r,c) with d == (r*64 + c*16) ^ ((r&7)<<4).
    // inverse: r = 2*(d>>7) | ((d>>6)^(d>>8))&1 ; c = ((d>>4)&3) ^ (r&3).
    const int d0 = t * 16;
    const int d1 = (t + 512) * 16;
    const int sr0 = ((d0 >> 7) << 1) | (((d0 >> 6) ^ (d0 >> 8)) & 1);
    const int sc0 = ((d0 >> 4) & 3) ^ (sr0 & 3);
    const int sr1 = ((d1 >> 7) << 1) | (((d1 >> 6) ^ (d1 >> 8)) & 1);
    const int sc1 = ((d1 >> 4) & 3) ^ (sr1 & 3);
    const int ga0 = (rowA + sr0) * K_DIM + sc0 * 8;
    const int ga1 = (rowA + sr1) * K_DIM + sc1 * 8;
    const int gb0 = (rowB + sr0) * K_DIM + sc0 * 8;
    const int e0 = t * 8, e1 = (t + 512) * 8;   // linear dest (elems)

#define STAGE_XL(sb, kk) do {                                \
    gld_lds16(Xb + ga0 + (kk), (sb) + e0);                   \
    gld_lds16(Xb + ga1 + (kk), (sb) + e1);                   \
    gld_lds16(Lb + ga0 + (kk), (sb) + 8192 + e0);            \
    gld_lds16(Lb + ga1 + (kk), (sb) + 8192 + e1);            \
} while (0)
#define STAGE_WG(sb, kk) do {                                \
    gld_lds16(Wt + gb0 + (kk), (sb) + 16384 + e0);           \
    gld_lds16(Gt + gb0 + (kk), (sb) + 20480 + e0);           \
} while (0)

    // ---- fragment read bases (byte offsets, swizzled), 32x32x16 pattern ------
    const int l31 = lane & 31;
    const int lc  = lane >> 5;          // k-chunk selector (0/1)
    const int swz = (l31 & 7) << 4;
    const int rbA0 = ((wm * 64 + l31) * 64 + lc * 16) ^ swz;        // kk=0
    const int rbA1 = ((wm * 64 + l31) * 64 + 32 + lc * 16) ^ swz;   // kk=1
    const int rbB0 = ((wn * 64 + l31) * 64 + lc * 16) ^ swz;
    const int rbB1 = ((wn * 64 + l31) * 64 + 32 + lc * 16) ^ swz;
    // mi/ni offset = +32 rows = +2048B (bit 11, outside mask; (row+32)&7 same).

#define MF32(A, B, C) __builtin_amdgcn_mfma_f32_32x32x16_bf16(A, B, C, 0, 0, 0)

#define CF()    asm volatile("" ::: "memory")
#define BAR()   do { CF(); __builtin_amdgcn_s_barrier(); CF(); } while (0)
#define LGKM0() do { asm volatile("s_waitcnt lgkmcnt(0)" ::: "memory"); \
                     __builtin_amdgcn_sched_barrier(0); } while (0)
#define PRIO1() __builtin_amdgcn_s_setprio(1)
#define PRIO0() __builtin_amdgcn_s_setprio(0)
#define VM12()  asm volatile("s_waitcnt vmcnt(12)" ::: "memory")
#define VM6()   asm volatile("s_waitcnt vmcnt(6)" ::: "memory")
#define VM0()   asm volatile("s_waitcnt vmcnt(0)" ::: "memory")

    // One K-step = 4 phases by (mi,ni) quadrant; 6 MFMA each (3 GEMMs x 2 kk).
#define STEP(CUR, SXL, SWG, VMW) do {                                      \
    const char* bse = (const char*)(CUR);                                  \
    /* PH0: 8 reads (ax0,al0,bw0,bg0), MFMA (0,0) */                       \
    short8 ax0k0 = *(const short8*)(bse + rbA0);                           \
    short8 ax0k1 = *(const short8*)(bse + rbA1);                           \
    short8 al0k0 = *(const short8*)(bse + 16384 + rbA0);                   \
    short8 al0k1 = *(const short8*)(bse + 16384 + rbA1);                   \
    short8 bw0k0 = *(const short8*)(bse + 32768 + rbB0);                   \
    short8 bw0k1 = *(const short8*)(bse + 32768 + rbB1);                   \
    short8 bg0k0 = *(const short8*)(bse + 40960 + rbB0);                   \
    short8 bg0k1 = *(const short8*)(bse + 40960 + rbB1);                   \
    BAR(); LGKM0(); PRIO1();                                               \
    acca[0][0] = MF32(ax0k0, bw0k0, acca[0][0]);                           \
    accm[0][0] = MF32(al0k0, bw0k0, accm[0][0]);                           \
    accg[0][0] = MF32(ax0k0, bg0k0, accg[0][0]);                           \
    acca[0][0] = MF32(ax0k1, bw0k1, acca[0][0]);                           \
    accm[0][0] = MF32(al0k1, bw0k1, accm[0][0]);                           \
    accg[0][0] = MF32(ax0k1, bg0k1, accg[0][0]);                           \
    PRIO0(); BAR();                                                        \
    /* PH1: 4 reads (ax1,al1), MFMA (1,0) — all X/L reads retire here */   \
    short8 ax1k0 = *(const short8*)(bse + 2048 + rbA0);                    \
    short8 ax1k1 = *(const short8*)(bse + 2048 + rbA1);                    \
    short8 al1k0 = *(const short8*)(bse + 16384 + 2048 + rbA0);            \
    short8 al1k1 = *(const short8*)(bse + 16384 + 2048 + rbA1);            \
    BAR(); LGKM0(); PRIO1();                                               \
    acca[1][0] = MF32(ax1k0, bw0k0, acca[1][0]);                           \
    accm[1][0] = MF32(al1k0, bw0k0, accm[1][0]);                           \
    accg[1][0] = MF32(ax1k0, bg0k0, accg[1][0]);                           \
    acca[1][0] = MF32(ax1k1, bw0k1, acca[1][0]);                           \
    accm[1][0] = MF32(al1k1, bw0k1, accm[1][0]);                           \
    accg[1][0] = MF32(ax1k1, bg0k1, accg[1][0]);                           \
    PRIO0(); BAR();                                                        \
    /* PH2: 4 reads (bw1,bg1); stage X/L (WAR-safe); MFMA (0,1) */         \
    short8 bw1k0 = *(const short8*)(bse + 32768 + 2048 + rbB0);            \
    short8 bw1k1 = *(const short8*)(bse + 32768 + 2048 + rbB1);            \
    short8 bg1k0 = *(const short8*)(bse + 40960 + 2048 + rbB0);            \
    short8 bg1k1 = *(const short8*)(bse + 40960 + 2048 + rbB1);            \
    SXL;                                                                   \
    BAR(); LGKM0(); PRIO1();                                               \
    acca[0][1] = MF32(ax0k0, bw1k0, acca[0][1]);                           \
    accm[0][1] = MF32(al0k0, bw1k0, accm[0][1]);                           \
    accg[0][1] = MF32(ax0k0, bg1k0, accg[0][1]);                           \
    acca[0][1] = MF32(ax0k1, bw1k1, acca[0][1]);                           \
    accm[0][1] = MF32(al0k1, bw1k1, accm[0][1]);                           \
    accg[0][1] = MF32(ax0k1, bg1k1, accg[0][1]);                           \
    PRIO0(); BAR();                                                        \
    /* PH3: stage W/G (WAR-safe); MFMA (1,1); counted vm */                \
    SWG;                                                                   \
    BAR(); PRIO1();                                                        \
    acca[1][1] = MF32(ax1k0, bw1k0, acca[1][1]);                           \
    accm[1][1] = MF32(al1k0, bw1k0, accm[1][1]);                           \
    accg[1][1] = MF32(ax1k0, bg1k0, accg[1][1]);                           \
    acca[1][1] = MF32(ax1k1, bw1k1, acca[1][1]);                           \
    accm[1][1] = MF32(al1k1, bw1k1, accm[1][1]);                           \
    accg[1][1] = MF32(ax1k1, bg1k1, accg[1][1]);                           \
    PRIO0(); VMW; BAR();                                                   \
} while (0)

    ushort* pb0 = smem;
    ushort* pb1 = smem + BUFE;
    ushort* pb2 = smem + 2 * BUFE;

    // prologue: fill 3 buffers (18 loads in flight), wait only for buffer 0
    STAGE_XL(pb0, 0);  STAGE_WG(pb0, 0);
    STAGE_XL(pb1, 32); STAGE_WG(pb1, 32);
    STAGE_XL(pb2, 64); STAGE_WG(pb2, 64);
    VM12();
    BAR();

    // steady state: j=0..60 stage K-step j+3 into CUR; tails j=61..63 drain
#pragma unroll 1
    for (int j = 0; j <= 60; ++j) {
        const int kst = (j + 3) * 32;
        STEP(pb0, STAGE_XL(pb0, kst), STAGE_WG(pb0, kst), VM12());
        ushort* tmp = pb0; pb0 = pb1; pb1 = pb2; pb2 = tmp;
    }
    STEP(pb0, ((void)0), ((void)0), VM6());
    { ushort* tmp = pb0; pb0 = pb1; pb1 = pb2; pb2 = tmp; }
    STEP(pb0, ((void)0), ((void)0), VM0());
    { ushort* tmp = pb0; pb0 = pb1; pb1 = pb2; pb2 = tmp; }
    STEP(pb0, ((void)0), ((void)0), ((void)0));

    // ---- epilogue: C/D col = lane&31 (128B-contiguous per half-wave) --------
#pragma unroll
    for (int mi = 0; mi < 2; mi++)
#pragma unroll
        for (int ni = 0; ni < 2; ni++)
#pragma unroll
            for (int r = 0; r < 16; r++) {
                int row = rowA + wm * 64 + mi * 32 + (r & 3) + 8 * (r >> 2) + 4 * lc;
                int col = rowB + wn * 64 + ni * 32 + l31;
                float g = 1.f / (1.f + __expf(-accg[mi][ni][r]));
                float a = acca[mi][ni][r];
                float m = __expf(accm[mi][ni][r]);
                out[(size_t)row * N_DIM + col] = g * a + (1.f - g) * m;
            }
}

extern "C" void kernel_launch(void* const* d_in, const int* in_sizes, int n_in,
                              void* d_out, int out_size, void* d_ws, size_t ws_size,
                              hipStream_t stream) {
    const float* X  = (const float*)d_in[0];
    const float* Wh = (const float*)d_in[1];
    const float* Mh = (const float*)d_in[2];
    const float* Gf = (const float*)d_in[3];
    float* out = (float*)d_out;

    // workspace layout (bytes):
    //   Xb : B*K*2  = 33,554,432
    //   Lb : B*K*2  = 33,554,432
    //   Wt : N*K*2  =  8,388,608   (transposed: [n][k])
    //   Gt : N*K*2  =  8,388,608
    char* ws = (char*)d_ws;
    ushort* Xb = (ushort*)(ws);
    ushort* Lb = (ushort*)(ws + (size_t)B_DIM * K_DIM * 2);
    ushort* Wt = (ushort*)(ws + (size_t)B_DIM * K_DIM * 4);
    ushort* Gt = (ushort*)(ws + (size_t)B_DIM * K_DIM * 4 + (size_t)N_DIM * K_DIM * 2);

    // 144KB dynamic LDS exceeds the default per-block cap — raise it once.
    static bool attr_set = false;
    if (!attr_set) {
        hipFuncSetAttribute((const void*)gemm_fused,
                            hipFuncAttributeMaxDynamicSharedMemorySize,
                            3 * BUFE * 2);
        attr_set = true;
    }

    prep_x<<<dim3((B_DIM * K_DIM) / (256 * 4)), dim3(256), 0, stream>>>(
        (const float4*)X, Xb, Lb);

    prep_wg<<<dim3(N_DIM / 32, K_DIM / 32), dim3(32, 8), 0, stream>>>(Wh, Mh, Gf, Wt, Gt);

    // 3 buffers x 48KB = 144KB dynamic LDS
    gemm_fused<<<dim3(N_DIM / 128, B_DIM / 256), dim3(512), 3 * BUFE * 2, stream>>>(
        Xb, Lb, Wt, Gt, out);
}

// Round 7
// 414.410 us; speedup vs baseline: 1.0595x; 1.0595x over previous
//
#include <hip/hip_runtime.h>
#include <stdint.h>

typedef __attribute__((ext_vector_type(8))) short short8;
typedef __attribute__((ext_vector_type(4))) float floatx4;

#define B_DIM 8192
#define K_DIM 2048
#define N_DIM 2048

// round-to-nearest-even fp32 -> bf16
__device__ __forceinline__ unsigned short f2bf(float f) {
    union { float f; unsigned u; } v; v.f = f;
    unsigned r = v.u + 0x7fffu + ((v.u >> 16) & 1u);
    return (unsigned short)(r >> 16);
}

__device__ __forceinline__ void gld_lds16(const void* g, void* l) {
    __builtin_amdgcn_global_load_lds(
        (const __attribute__((address_space(1))) void*)g,
        (__attribute__((address_space(3))) void*)l, 16, 0, 0);
}

// ---------------- prepass 1: X -> Xb (bf16), Lb = bf16(log(|x|+eps)) ----------------
__global__ __launch_bounds__(256) void prep_x(const float4* __restrict__ X4,
                                              ushort* __restrict__ Xb,
                                              ushort* __restrict__ Lb) {
    int i = blockIdx.x * 256 + threadIdx.x;
    float4 v = X4[i];
    ushort4 xb, lb;
    xb.x = f2bf(v.x); xb.y = f2bf(v.y); xb.z = f2bf(v.z); xb.w = f2bf(v.w);
    lb.x = f2bf(__logf(fabsf(v.x) + 1e-7f));
    lb.y = f2bf(__logf(fabsf(v.y) + 1e-7f));
    lb.z = f2bf(__logf(fabsf(v.z) + 1e-7f));
    lb.w = f2bf(__logf(fabsf(v.w) + 1e-7f));
    *(ushort4*)(Xb + (size_t)i * 4) = xb;
    *(ushort4*)(Lb + (size_t)i * 4) = lb;
}

// ---------------- prepass 2: Wt[n][k] = bf16(tanh(Wh)*sigmoid(Mh)), Gt[n][k] = bf16(gate) ----
__global__ __launch_bounds__(256) void prep_wg(const float* __restrict__ Wh,
                                               const float* __restrict__ Mh,
                                               const float* __restrict__ Gf,
                                               ushort* __restrict__ Wt,
                                               ushort* __restrict__ Gt) {
    __shared__ float tw[32][33];
    __shared__ float tg[32][33];
    const int k0 = blockIdx.y * 32, n0 = blockIdx.x * 32;
    const int tx = threadIdx.x, ty = threadIdx.y;  // 32 x 8
#pragma unroll
    for (int i = 0; i < 4; i++) {
        int k = k0 + ty + i * 8;
        int n = n0 + tx;
        size_t idx = (size_t)k * N_DIM + n;
        float wh = Wh[idx], mh = Mh[idx];
        float e2 = __expf(2.f * wh);
        float th = 1.f - 2.f / (e2 + 1.f);          // tanh(wh)
        tw[ty + i * 8][tx] = th * (1.f / (1.f + __expf(-mh)));
        tg[ty + i * 8][tx] = Gf[idx];
    }
    __syncthreads();
#pragma unroll
    for (int i = 0; i < 4; i++) {
        int n = n0 + ty + i * 8;
        int k = k0 + tx;
        Wt[(size_t)n * K_DIM + k] = f2bf(tw[tx][ty + i * 8]);
        Gt[(size_t)n * K_DIM + k] = f2bf(tg[tx][ty + i * 8]);
    }
}

// ---------------- fused GEMM: a = Xb@Wt^T, lm = Lb@Wt^T, gl = Xb@Gt^T ----------------
// out = sigmoid(gl)*a + (1-sigmoid(gl))*exp(lm)
//
// Round-7: r5's verified 4-phase counted-vmcnt schedule (267us, MfmaUtil 33%,
// 16x16x32 MFMA — r6's 32x32 shape REVERTED: depth-2 acc chains with only 3
// independent chains/phase starved the pipe, 324us), ONE lever changed:
//   * BM 256->128 (r1's verified 256-thread/4-wave geometry, 2 x 32KB LDS
//     buffers = 64KB) -> TWO blocks per CU. r5's single 144KB block barrier-
//     locks all 8 waves into the same phase, so LDS-read windows and MFMA
//     windows strictly alternate (pipes never overlap; >=1700cy/K-step dead).
//     Two desynchronized blocks co-schedule (m114: time ~ max, not sum):
//     block A's read window overlaps block B's MFMA window.
// Schedule per K-step (per block): 4 phases by acc quadrant, each
// {ds_reads; BAR; lgkmcnt0+sched_barrier; setprio1; 12 indep MFMA; setprio0;
// BAR}. Stage in PH3 into the CURRENT buffer (2-buffer ring, j+2 = j mod 2):
// all reads retired at PH2's closing barrier -> WAR safe. VM8 at step j
// completes step j+1's 8 loads with a full K-step of slack; main loop never
// drains vmcnt(0).
// Carried: T2 XOR bank-swizzle (rule #21: linear gld_lds dest, swizzle-inverse
// GLOBAL source, XOR on read address; 2-way max on 16-lane service = free).
// Ledger: SQ_LDS_BANK_CONFLICT pegged at 2^24 every round -> saturated
// artifact, not a signal.
#define SEC  (128 * 32)        // elems per section (8 KB)
#define BUFE (4 * SEC)         // elems per buffer  (32 KB): X | L | W | G

__global__ __launch_bounds__(256, 2) void gemm_fused(const ushort* __restrict__ Xb,
                                                     const ushort* __restrict__ Lb,
                                                     const ushort* __restrict__ Wt,
                                                     const ushort* __restrict__ Gt,
                                                     float* __restrict__ out) {
    __shared__ ushort smem[2 * BUFE];   // 64 KB -> 2 blocks/CU

    const int t = threadIdx.x;
    const int lane = t & 63;
    const int w = t >> 6;               // 0..3
    const int wm = w >> 1, wn = w & 1;
    const int rowA = blockIdx.y * 128;  // M tile base
    const int rowB = blockIdx.x * 128;  // N tile base

    floatx4 acca[4][4], accm[4][4], accg[4][4];
    const floatx4 z = {0.f, 0.f, 0.f, 0.f};
#pragma unroll
    for (int i = 0; i < 4; i++)
#pragma unroll
        for (int j = 0; j < 4; j++) { acca[i][j] = z; accm[i][j] = z; accg[i][j] = z; }

    // ---- staging: swizzle-inverse source coordinates -------------------------
    // dest byte d holds global (r,c) with d == (r*64 + c*16) ^ ((r&7)<<4).
    // inverse: r = 2*(d>>7) | ((d>>6)^(d>>8))&1 ; c = ((d>>4)&3) ^ (r&3).
    const int d0 = t * 16;
    const int d1 = (t + 256) * 16;
    const int sr0 = ((d0 >> 7) << 1) | (((d0 >> 6) ^ (d0 >> 8)) & 1);
    const int sc0 = ((d0 >> 4) & 3) ^ (sr0 & 3);
    const int sr1 = ((d1 >> 7) << 1) | (((d1 >> 6) ^ (d1 >> 8)) & 1);
    const int sc1 = ((d1 >> 4) & 3) ^ (sr1 & 3);
    const int ga0 = (rowA + sr0) * K_DIM + sc0 * 8;
    const int ga1 = (rowA + sr1) * K_DIM + sc1 * 8;
    const int gb0 = (rowB + sr0) * K_DIM + sc0 * 8;
    const int gb1 = (rowB + sr1) * K_DIM + sc1 * 8;
    const int e0 = t * 8, e1 = (t + 256) * 8;   // linear dest (elems)

#define STAGE(sb, kk) do {                                   \
    gld_lds16(Xb + ga0 + (kk), (sb) + e0);                   \
    gld_lds16(Xb + ga1 + (kk), (sb) + e1);                   \
    gld_lds16(Lb + ga0 + (kk), (sb) + SEC + e0);             \
    gld_lds16(Lb + ga1 + (kk), (sb) + SEC + e1);             \
    gld_lds16(Wt + gb0 + (kk), (sb) + 2 * SEC + e0);         \
    gld_lds16(Wt + gb1 + (kk), (sb) + 2 * SEC + e1);         \
    gld_lds16(Gt + gb0 + (kk), (sb) + 3 * SEC + e0);         \
    gld_lds16(Gt + gb1 + (kk), (sb) + 3 * SEC + e1);         \
} while (0)

    // ---- fragment read bases (byte offsets, swizzled) ------------------------
    const int lr = lane & 15;
    const int rbA = (((wm * 64 + lr) * 64) + ((lane >> 4) * 16)) ^ ((lr & 7) << 4);
    const int rbB = (((wn * 64 + lr) * 64) + ((lane >> 4) * 16)) ^ ((lr & 7) << 4);
    // per-mi/ni offsets +1024B (16 rows) are in bits >=10: no swizzle overlap.

#define TRIP(MI, NI, AX, AL, BW, BG)                                                        \
    acca[MI][NI] = __builtin_amdgcn_mfma_f32_16x16x32_bf16(AX, BW, acca[MI][NI], 0, 0, 0);  \
    accm[MI][NI] = __builtin_amdgcn_mfma_f32_16x16x32_bf16(AL, BW, accm[MI][NI], 0, 0, 0);  \
    accg[MI][NI] = __builtin_amdgcn_mfma_f32_16x16x32_bf16(AX, BG, accg[MI][NI], 0, 0, 0);

#define CF()    asm volatile("" ::: "memory")
#define BAR()   do { CF(); __builtin_amdgcn_s_barrier(); CF(); } while (0)
#define LGKM0() do { asm volatile("s_waitcnt lgkmcnt(0)" ::: "memory"); \
                     __builtin_amdgcn_sched_barrier(0); } while (0)
#define PRIO1() __builtin_amdgcn_s_setprio(1)
#define PRIO0() __builtin_amdgcn_s_setprio(0)
#define VM8()   asm volatile("s_waitcnt vmcnt(8)" ::: "memory")
#define VM0()   asm volatile("s_waitcnt vmcnt(0)" ::: "memory")

    // One K-step = 4 phases by acc quadrant; 12 independent MFMAs per phase.
    // Reads: PH0 ax0,ax1,al0,al1,bw0,bw1,bg0,bg1; PH1 bw2,bw3,bg2,bg3;
    // PH2 ax2,ax3,al2,al3 (last reads). PH3: STAGE (WAR-safe) + counted vm.
#define STEP(CUR, STG, VMW) do {                                           \
    const char* bA  = (const char*)(CUR) + rbA;                            \
    const char* bAl = (const char*)(CUR) + 2 * SEC + rbA;                  \
    const char* bB  = (const char*)(CUR) + 4 * SEC + rbB;                  \
    const char* bBg = (const char*)(CUR) + 6 * SEC + rbB;                  \
    /* PH0 */                                                              \
    short8 ax0 = *(const short8*)(bA);                                     \
    short8 ax1 = *(const short8*)(bA + 1024);                              \
    short8 al0 = *(const short8*)(bAl);                                    \
    short8 al1 = *(const short8*)(bAl + 1024);                             \
    short8 bw0 = *(const short8*)(bB);                                     \
    short8 bw1 = *(const short8*)(bB + 1024);                              \
    short8 bg0 = *(const short8*)(bBg);                                    \
    short8 bg1 = *(const short8*)(bBg + 1024);                             \
    BAR(); LGKM0(); PRIO1();                                               \
    TRIP(0,0,ax0,al0,bw0,bg0) TRIP(0,1,ax0,al0,bw1,bg1)                    \
    TRIP(1,0,ax1,al1,bw0,bg0) TRIP(1,1,ax1,al1,bw1,bg1)                    \
    PRIO0(); BAR();                                                        \
    /* PH1 */                                                              \
    short8 bw2 = *(const short8*)(bB + 2048);                              \
    short8 bw3 = *(const short8*)(bB + 3072);                              \
    short8 bg2 = *(const short8*)(bBg + 2048);                             \
    short8 bg3 = *(const short8*)(bBg + 3072);                             \
    BAR(); LGKM0(); PRIO1();                                               \
    TRIP(0,2,ax0,al0,bw2,bg2) TRIP(0,3,ax0,al0,bw3,bg3)                    \
    TRIP(1,2,ax1,al1,bw2,bg2) TRIP(1,3,ax1,al1,bw3,bg3)                    \
    PRIO0(); BAR();                                                        \
    /* PH2 (last ds_reads of this buffer) */                               \
    short8 ax2 = *(const short8*)(bA + 2048);                              \
    short8 ax3 = *(const short8*)(bA + 3072);                              \
    short8 al2 = *(const short8*)(bAl + 2048);                             \
    short8 al3 = *(const short8*)(bAl + 3072);                             \
    BAR(); LGKM0(); PRIO1();                                               \
    TRIP(2,0,ax2,al2,bw0,bg0) TRIP(2,1,ax2,al2,bw1,bg1)                    \
    TRIP(3,0,ax3,al3,bw0,bg0) TRIP(3,1,ax3,al3,bw1,bg1)                    \
    PRIO0(); BAR();                                                        \
    /* PH3: stage into CUR (all reads retired), counted vm */              \
    STG;                                                                   \
    BAR(); PRIO1();                                                        \
    TRIP(2,2,ax2,al2,bw2,bg2) TRIP(2,3,ax2,al2,bw3,bg3)                    \
    TRIP(3,2,ax3,al3,bw2,bg2) TRIP(3,3,ax3,al3,bw3,bg3)                    \
    PRIO0(); VMW; BAR();                                                   \
} while (0)

    ushort* pc = smem;          // current buffer
    ushort* pn = smem + BUFE;   // next buffer

    // prologue: fill both buffers (16 loads); wait for buffer 0's 8 only
    STAGE(pc, 0);
    STAGE(pn, 32);
    VM8();
    BAR();

    // steady state: step j consumes buf j%2; stages K-step j+2 into the SAME
    // buffer (ring of 2). VM8 at step j completes step j+1's loads.
#pragma unroll 1
    for (int j = 0; j <= 61; ++j) {
        STEP(pc, STAGE(pc, (j + 2) * 32), VM8());
        ushort* tmp = pc; pc = pn; pn = tmp;
    }
    STEP(pc, ((void)0), VM0());        // j=62: drain step 63's 8 loads
    { ushort* tmp = pc; pc = pn; pn = tmp; }
    STEP(pc, ((void)0), ((void)0));    // j=63

    // ---- epilogue (verified r1 layout) --------------------------------------
    const int rsub = (lane >> 4) << 2;
#pragma unroll
    for (int mi = 0; mi < 4; mi++)
#pragma unroll
        for (int ni = 0; ni < 4; ni++)
#pragma unroll
            for (int r = 0; r < 4; r++) {
                int row = rowA + wm * 64 + mi * 16 + rsub + r;
                int col = rowB + wn * 64 + ni * 16 + lr;
                float g = 1.f / (1.f + __expf(-accg[mi][ni][r]));
                float a = acca[mi][ni][r];
                float m = __expf(accm[mi][ni][r]);
                out[(size_t)row * N_DIM + col] = g * a + (1.f - g) * m;
            }
}

extern "C" void kernel_launch(void* const* d_in, const int* in_sizes, int n_in,
                              void* d_out, int out_size, void* d_ws, size_t ws_size,
                              hipStream_t stream) {
    const float* X  = (const float*)d_in[0];
    const float* Wh = (const float*)d_in[1];
    const float* Mh = (const float*)d_in[2];
    const float* Gf = (const float*)d_in[3];
    float* out = (float*)d_out;

    // workspace layout (bytes):
    //   Xb : B*K*2  = 33,554,432
    //   Lb : B*K*2  = 33,554,432
    //   Wt : N*K*2  =  8,388,608   (transposed: [n][k])
    //   Gt : N*K*2  =  8,388,608
    char* ws = (char*)d_ws;
    ushort* Xb = (ushort*)(ws);
    ushort* Lb = (ushort*)(ws + (size_t)B_DIM * K_DIM * 2);
    ushort* Wt = (ushort*)(ws + (size_t)B_DIM * K_DIM * 4);
    ushort* Gt = (ushort*)(ws + (size_t)B_DIM * K_DIM * 4 + (size_t)N_DIM * K_DIM * 2);

    prep_x<<<dim3((B_DIM * K_DIM) / (256 * 4)), dim3(256), 0, stream>>>(
        (const float4*)X, Xb, Lb);

    prep_wg<<<dim3(N_DIM / 32, K_DIM / 32), dim3(32, 8), 0, stream>>>(Wh, Mh, Gf, Wt, Gt);

    gemm_fused<<<dim3(N_DIM / 128, B_DIM / 128), dim3(256), 0, stream>>>(Xb, Lb, Wt, Gt, out);
}